// Round 8
// baseline (3024.613 us; speedup 1.0000x reference)
//
#include <hip/hip_runtime.h>

#define N_NODES 100000
#define NUM_U 50000
#define D 64
#define NUM_E 3200000
#define NB 391                 // ceil(100000/256) buckets of 256 dst nodes
#define PBLK 256               // partition blocks
#define CHUNK (NUM_E / PBLK)   // 12500 edges per partition block

// ---- micro: M = (W2@W1)^T (row k, col j), c = b1@W2^T, cc = 0.5c+b2 ----
__global__ __launch_bounds__(256) void micro_kernel(
    const float* __restrict__ W1, const float* __restrict__ W2,
    const float* __restrict__ b1, const float* __restrict__ b2,
    float* __restrict__ M, float* __restrict__ c, float* __restrict__ cc) {
  __shared__ float w1[64][65], w2[64][65];
  int t = (int)threadIdx.x;
  for (int i = t; i < 4096; i += 256) { w1[i >> 6][i & 63] = W1[i]; w2[i >> 6][i & 63] = W2[i]; }
  __syncthreads();
  for (int i = t; i < 4096; i += 256) {
    int k = i >> 6, j = i & 63;
    float s = 0.f;
#pragma unroll
    for (int tt = 0; tt < 64; ++tt) s = fmaf(w2[j][tt], w1[tt][k], s);
    M[i] = s;  // M[k][j]
  }
  if (t < 64) {
    float s = 0.f;
#pragma unroll
    for (int tt = 0; tt < 64; ++tt) s = fmaf(b1[tt], w2[t][tt], s);
    c[t] = s;
    cc[t] = 0.5f * s + b2[t];
  }
}

// ---- z = x @ M (x = concat(user,item) via per-row pointer select) ----
__global__ __launch_bounds__(256) void zmm_kernel(
    const float* __restrict__ xu, const float* __restrict__ xi,
    const float* __restrict__ M, float* __restrict__ z) {
  __shared__ float Mt[64][65];  // Mt[j][k] = M[k][j]
  __shared__ float U[64][65];
  int t = (int)threadIdx.x;
  for (int i = t; i < 4096; i += 256) Mt[i & 63][i >> 6] = M[i];
  int lane = t & 63, row = t >> 6;
  int n0 = (int)blockIdx.x * 64;
#pragma unroll
  for (int i = 0; i < 16; ++i) {
    int nl = row + 4 * i, n = n0 + nl;
    if (n < N_NODES) {
      const float* xr = (n < NUM_U) ? (xu + (size_t)n * D) : (xi + (size_t)(n - NUM_U) * D);
      U[nl][lane] = xr[lane];
    }
  }
  __syncthreads();
#pragma unroll
  for (int i = 0; i < 16; ++i) {
    int nl = row + 4 * i, n = n0 + nl;
    if (n >= N_NODES) continue;
    float s = 0.f;
#pragma unroll
    for (int k = 0; k < 64; ++k) s = fmaf(U[nl][k], Mt[lane][k], s);
    z[(size_t)n * D + lane] = s;
  }
}

// ---- P1: per-block bucket histogram (LDS) + global totals ----
__global__ __launch_bounds__(256) void p1_hist(const int4* __restrict__ dst4,
                                               int* __restrict__ gcnt,
                                               int* __restrict__ tot) {
  __shared__ int h[NB];
  int t = (int)threadIdx.x, blk = (int)blockIdx.x;
  for (int i = t; i < NB; i += 256) h[i] = 0;
  __syncthreads();
  int base4 = blk * (CHUNK / 4);
  for (int i = t; i < CHUNK / 4; i += 256) {
    int4 d = dst4[base4 + i];
    atomicAdd(&h[d.x >> 8], 1); atomicAdd(&h[d.y >> 8], 1);
    atomicAdd(&h[d.z >> 8], 1); atomicAdd(&h[d.w >> 8], 1);
  }
  __syncthreads();
  for (int i = t; i < NB; i += 256) {
    gcnt[i * PBLK + blk] = h[i];
    atomicAdd(&tot[i], h[i]);
  }
}

// ---- P2a: exclusive scan of bucket totals -> bbase ----
__global__ __launch_bounds__(512) void p2_scan(const int* __restrict__ tot,
                                               int* __restrict__ bbase) {
  __shared__ int ps[512];
  int t = (int)threadIdx.x;
  int v = (t < NB) ? tot[t] : 0;
  ps[t] = v;
  __syncthreads();
  for (int off = 1; off < 512; off <<= 1) {
    int a = (t >= off) ? ps[t - off] : 0;
    __syncthreads();
    ps[t] += a;
    __syncthreads();
  }
  if (t < NB) bbase[t] = ps[t] - v;
  if (t == 0) bbase[NB] = NUM_E;
}

// ---- P2b: per-(bucket,block) write offsets ----
__global__ __launch_bounds__(256) void p2_off(const int* __restrict__ gcnt,
                                              const int* __restrict__ bbase,
                                              int* __restrict__ off) {
  __shared__ int ps[256];
  int t = (int)threadIdx.x, b = (int)blockIdx.x;
  int v = gcnt[b * PBLK + t];
  ps[t] = v;
  __syncthreads();
  for (int o = 1; o < 256; o <<= 1) {
    int a = (t >= o) ? ps[t - o] : 0;
    __syncthreads();
    ps[t] += a;
    __syncthreads();
  }
  off[b * PBLK + t] = bbase[b] + ps[t] - v;
}

// ---- P3: partition edges into dense bucket-major staging ----
__global__ __launch_bounds__(256) void p3_part(const int4* __restrict__ src4,
                                               const int4* __restrict__ dst4,
                                               const float4* __restrict__ w4,
                                               const int* __restrict__ off,
                                               int2* __restrict__ staging) {
  __shared__ int cur[NB];
  int t = (int)threadIdx.x, blk = (int)blockIdx.x;
  for (int i = t; i < NB; i += 256) cur[i] = off[i * PBLK + blk];
  __syncthreads();
  int base4 = blk * (CHUNK / 4);
  for (int i = t; i < CHUNK / 4; i += 256) {
    int4 s = src4[base4 + i];
    int4 d = dst4[base4 + i];
    float4 w = w4[base4 + i];
    int p;
    p = atomicAdd(&cur[d.x >> 8], 1);
    staging[p] = make_int2(s.x | ((d.x & 255) << 17), __float_as_int(w.x));
    p = atomicAdd(&cur[d.y >> 8], 1);
    staging[p] = make_int2(s.y | ((d.y & 255) << 17), __float_as_int(w.y));
    p = atomicAdd(&cur[d.z >> 8], 1);
    staging[p] = make_int2(s.z | ((d.z & 255) << 17), __float_as_int(w.z));
    p = atomicAdd(&cur[d.w >> 8], 1);
    staging[p] = make_int2(s.w | ((d.w & 255) << 17), __float_as_int(w.w));
  }
}

// ---- G: bucketed LDS aggregation. One block per bucket (256 dst nodes).
// acc stride 65 (65 == 1 mod 32 -> rows phase-shift banks); col 64 = wsum.
// 4 edges per wave pass: 16 lanes x float4 = 1 dwordx4 per 256B row.
template <bool FINAL>
__global__ __launch_bounds__(256) void gather_kernel(
    const int* __restrict__ bbase, const int2* __restrict__ staging,
    const float* __restrict__ gsrc, const float* __restrict__ zorig,
    const float* __restrict__ cvec, const float* __restrict__ ccvec,
    float* __restrict__ outp) {
  __shared__ float acc[256 * 65];
  __shared__ float cls[64], ccls[64];
  int t = (int)threadIdx.x;
  int b = (int)blockIdx.x;
  for (int i = t; i < 256 * 65; i += 256) acc[i] = 0.f;
  if (FINAL && t < 64) { cls[t] = cvec[t]; ccls[t] = ccvec[t]; }
  __syncthreads();

  int bs = bbase[b], be = bbase[b + 1];
  int lane = t & 63, wv = t >> 6;  // wave 0..3
  int sub = lane >> 4;             // 4-edge subgroup
  int lq = lane & 15;              // lane within 16

  for (int ts = bs + wv * 64; ts < be; ts += 256) {
    int j = ts + lane;
    int2 m = (j < be) ? staging[j] : make_int2(0, 0);
#pragma unroll
    for (int k = 0; k < 16; ++k) {
      int idx = 4 * k + sub;
      int sp = __shfl(m.x, idx);
      float wp = __int_as_float(__shfl(m.y, idx));
      if (ts + idx < be) {
        int s = sp & 0x1FFFF;
        int dl = sp >> 17;
        const float4 v = *(const float4*)(gsrc + (size_t)s * D + lq * 4);
        float* a = &acc[dl * 65 + lq * 4];
        atomicAdd(&a[0], v.x * wp);
        atomicAdd(&a[1], v.y * wp);
        atomicAdd(&a[2], v.z * wp);
        atomicAdd(&a[3], v.w * wp);
        if (FINAL && lq == 0) atomicAdd(&acc[dl * 65 + 64], wp);
      }
    }
  }
  __syncthreads();

  int n0 = b * 256;
  for (int i = t; i < 256 * 64; i += 256) {
    int r = i >> 6, c = i & 63;
    int n = n0 + r;
    if (n >= N_NODES) continue;
    float a = acc[r * 65 + c];
    if (FINAL) {
      float ws = acc[r * 65 + 64];
      float t1v = gsrc[(size_t)n * D + c];
      float zv = zorig[(size_t)n * D + c];
      outp[(size_t)n * D + c] =
          0.25f * a + 0.5f * t1v + 0.25f * zv + 0.5f * ws * cls[c] + ccls[c];
    } else {
      outp[(size_t)n * D + c] = a;
    }
  }
}

extern "C" void kernel_launch(void* const* d_in, const int* in_sizes, int n_in,
                              void* d_out, int out_size, void* d_ws, size_t ws_size,
                              hipStream_t stream) {
  const int* edge_index = (const int*)d_in[0];
  const int* src = edge_index;          // row 0
  const int* dst = edge_index + NUM_E;  // row 1
  const float* w = (const float*)d_in[1];
  const float* user_emb = (const float*)d_in[2];
  const float* item_emb = (const float*)d_in[3];
  const float* W1 = (const float*)d_in[4];
  const float* b1 = (const float*)d_in[5];
  const float* W2 = (const float*)d_in[6];
  const float* b2 = (const float*)d_in[7];
  float* out = (float*)d_out;

  // workspace layout (~77.6 MB, under the proven 78.2 MB)
  float* z = (float*)d_ws;                           // N*D floats
  float* t1 = z + (size_t)N_NODES * D;               // N*D floats
  int2* staging = (int2*)(t1 + (size_t)N_NODES * D); // E int2 (dense)
  int* gcnt = (int*)(staging + NUM_E);               // NB*PBLK
  int* off = gcnt + NB * PBLK;                       // NB*PBLK
  int* tot = off + NB * PBLK;                        // NB (pad 392)
  int* bbase = tot + 392;                            // NB+1 (pad 392)
  float* Mbuf = (float*)(bbase + 392);               // 4096
  float* cbuf = Mbuf + 4096;                         // 64
  float* ccbuf = cbuf + 64;                          // 64

  hipMemsetAsync(tot, 0, NB * sizeof(int), stream);

  micro_kernel<<<1, 256, 0, stream>>>(W1, W2, b1, b2, Mbuf, cbuf, ccbuf);
  zmm_kernel<<<(N_NODES + 63) / 64, 256, 0, stream>>>(user_emb, item_emb, Mbuf, z);

  p1_hist<<<PBLK, 256, 0, stream>>>((const int4*)dst, gcnt, tot);
  p2_scan<<<1, 512, 0, stream>>>(tot, bbase);
  p2_off<<<NB, 256, 0, stream>>>(gcnt, bbase, off);
  p3_part<<<PBLK, 256, 0, stream>>>((const int4*)src, (const int4*)dst,
                                    (const float4*)w, off, staging);

  // t1 = S @ z
  gather_kernel<false><<<NB, 256, 0, stream>>>(bbase, staging, z, z, cbuf, ccbuf, t1);
  // out = 0.25*S@t1 + 0.5*t1 + 0.25*z + 0.5*dw*c + cc
  gather_kernel<true><<<NB, 256, 0, stream>>>(bbase, staging, t1, z, cbuf, ccbuf, out);
}

// Round 9
// 498.359 us; speedup vs baseline: 6.0691x; 6.0691x over previous
//
#include <hip/hip_runtime.h>

#define N_NODES 100000
#define NUM_U 50000
#define D 64
#define NUM_E 3200000
#define NB 391                 // ceil(100000/256) buckets of 256 dst nodes
#define PBLK 256               // partition blocks
#define CHUNK (NUM_E / PBLK)   // 12500 edges per partition block

// ---- micro: M = (W2@W1)^T (row k, col j), c = b1@W2^T, cc = 0.5c+b2 ----
__global__ __launch_bounds__(256) void micro_kernel(
    const float* __restrict__ W1, const float* __restrict__ W2,
    const float* __restrict__ b1, const float* __restrict__ b2,
    float* __restrict__ M, float* __restrict__ c, float* __restrict__ cc) {
  __shared__ float w1[64][65], w2[64][65];
  int t = (int)threadIdx.x;
  for (int i = t; i < 4096; i += 256) { w1[i >> 6][i & 63] = W1[i]; w2[i >> 6][i & 63] = W2[i]; }
  __syncthreads();
  for (int i = t; i < 4096; i += 256) {
    int k = i >> 6, j = i & 63;
    float s = 0.f;
#pragma unroll
    for (int tt = 0; tt < 64; ++tt) s = fmaf(w2[j][tt], w1[tt][k], s);
    M[i] = s;  // M[k][j]
  }
  if (t < 64) {
    float s = 0.f;
#pragma unroll
    for (int tt = 0; tt < 64; ++tt) s = fmaf(b1[tt], w2[t][tt], s);
    c[t] = s;
    cc[t] = 0.5f * s + b2[t];
  }
}

// ---- z = x @ M (x = concat(user,item) via per-row pointer select) ----
__global__ __launch_bounds__(256) void zmm_kernel(
    const float* __restrict__ xu, const float* __restrict__ xi,
    const float* __restrict__ M, float* __restrict__ z) {
  __shared__ float Mt[64][65];  // Mt[j][k] = M[k][j]
  __shared__ float U[64][65];
  int t = (int)threadIdx.x;
  for (int i = t; i < 4096; i += 256) Mt[i & 63][i >> 6] = M[i];
  int lane = t & 63, row = t >> 6;
  int n0 = (int)blockIdx.x * 64;
#pragma unroll
  for (int i = 0; i < 16; ++i) {
    int nl = row + 4 * i, n = n0 + nl;
    if (n < N_NODES) {
      const float* xr = (n < NUM_U) ? (xu + (size_t)n * D) : (xi + (size_t)(n - NUM_U) * D);
      U[nl][lane] = xr[lane];
    }
  }
  __syncthreads();
#pragma unroll
  for (int i = 0; i < 16; ++i) {
    int nl = row + 4 * i, n = n0 + nl;
    if (n >= N_NODES) continue;
    float s = 0.f;
#pragma unroll
    for (int k = 0; k < 64; ++k) s = fmaf(U[nl][k], Mt[lane][k], s);
    z[(size_t)n * D + lane] = s;
  }
}

// ---- P1: per-block bucket histogram (LDS) + global totals ----
__global__ __launch_bounds__(256) void p1_hist(const int4* __restrict__ dst4,
                                               int* __restrict__ gcnt,
                                               int* __restrict__ tot) {
  __shared__ int h[NB];
  int t = (int)threadIdx.x, blk = (int)blockIdx.x;
  for (int i = t; i < NB; i += 256) h[i] = 0;
  __syncthreads();
  int base4 = blk * (CHUNK / 4);
  for (int i = t; i < CHUNK / 4; i += 256) {
    int4 d = dst4[base4 + i];
    atomicAdd(&h[d.x >> 8], 1); atomicAdd(&h[d.y >> 8], 1);
    atomicAdd(&h[d.z >> 8], 1); atomicAdd(&h[d.w >> 8], 1);
  }
  __syncthreads();
  for (int i = t; i < NB; i += 256) {
    gcnt[i * PBLK + blk] = h[i];
    atomicAdd(&tot[i], h[i]);
  }
}

// ---- P2a: exclusive scan of bucket totals -> bbase; also rowptr[N]=E ----
__global__ __launch_bounds__(512) void p2_scan(const int* __restrict__ tot,
                                               int* __restrict__ bbase,
                                               int* __restrict__ rowptr) {
  __shared__ int ps[512];
  int t = (int)threadIdx.x;
  int v = (t < NB) ? tot[t] : 0;
  ps[t] = v;
  __syncthreads();
  for (int off = 1; off < 512; off <<= 1) {
    int a = (t >= off) ? ps[t - off] : 0;
    __syncthreads();
    ps[t] += a;
    __syncthreads();
  }
  if (t < NB) bbase[t] = ps[t] - v;
  if (t == 0) { bbase[NB] = NUM_E; rowptr[N_NODES] = NUM_E; }
}

// ---- P2b: per-(bucket,block) write offsets ----
__global__ __launch_bounds__(256) void p2_off(const int* __restrict__ gcnt,
                                              const int* __restrict__ bbase,
                                              int* __restrict__ off) {
  __shared__ int ps[256];
  int t = (int)threadIdx.x, b = (int)blockIdx.x;
  int v = gcnt[b * PBLK + t];
  ps[t] = v;
  __syncthreads();
  for (int o = 1; o < 256; o <<= 1) {
    int a = (t >= o) ? ps[t - o] : 0;
    __syncthreads();
    ps[t] += a;
    __syncthreads();
  }
  off[b * PBLK + t] = bbase[b] + ps[t] - v;
}

// ---- P3: partition edges into dense bucket-major staging ----
__global__ __launch_bounds__(256) void p3_part(const int4* __restrict__ src4,
                                               const int4* __restrict__ dst4,
                                               const float4* __restrict__ w4,
                                               const int* __restrict__ off,
                                               int2* __restrict__ staging) {
  __shared__ int cur[NB];
  int t = (int)threadIdx.x, blk = (int)blockIdx.x;
  for (int i = t; i < NB; i += 256) cur[i] = off[i * PBLK + blk];
  __syncthreads();
  int base4 = blk * (CHUNK / 4);
  for (int i = t; i < CHUNK / 4; i += 256) {
    int4 s = src4[base4 + i];
    int4 d = dst4[base4 + i];
    float4 w = w4[base4 + i];
    int p;
    p = atomicAdd(&cur[d.x >> 8], 1);
    staging[p] = make_int2(s.x | ((d.x & 255) << 17), __float_as_int(w.x));
    p = atomicAdd(&cur[d.y >> 8], 1);
    staging[p] = make_int2(s.y | ((d.y & 255) << 17), __float_as_int(w.y));
    p = atomicAdd(&cur[d.z >> 8], 1);
    staging[p] = make_int2(s.z | ((d.z & 255) << 17), __float_as_int(w.z));
    p = atomicAdd(&cur[d.w >> 8], 1);
    staging[p] = make_int2(s.w | ((d.w & 255) << 17), __float_as_int(w.w));
  }
}

// ---- F: per-bucket CSR finalize. One block per bucket; all scattered writes
// land in the bucket's own contiguous ~64KB range (single-XCD L2 resident ->
// full-line writebacks once; kills fill's 8x write amplification).
__global__ __launch_bounds__(256) void csr_finalize(
    const int* __restrict__ bbase, const int2* __restrict__ staging,
    int2* __restrict__ meta, int* __restrict__ rowptr) {
  __shared__ int hist[256];
  __shared__ int ps[256];
  __shared__ int cur[256];
  int t = (int)threadIdx.x, b = (int)blockIdx.x;
  int bs = bbase[b], be = bbase[b + 1];
  hist[t] = 0;
  __syncthreads();
  for (int i = bs + t; i < be; i += 256) atomicAdd(&hist[staging[i].x >> 17], 1);
  __syncthreads();
  int v = hist[t];
  ps[t] = v;
  __syncthreads();
  for (int o = 1; o < 256; o <<= 1) {
    int a = (t >= o) ? ps[t - o] : 0;
    __syncthreads();
    ps[t] += a;
    __syncthreads();
  }
  int base = bs + ps[t] - v;  // exclusive
  cur[t] = base;
  int n = b * 256 + t;
  if (n < N_NODES) rowptr[n] = base;
  __syncthreads();
  for (int i = bs + t; i < be; i += 256) {
    int2 m = staging[i];
    int dl = m.x >> 17;
    int p = atomicAdd(&cur[dl], 1);
    meta[p] = make_int2(m.x & 0x1FFFF, m.y);
  }
}

// ---- G: pure gather (round-5 proven): wave per node, lane = dim,
// 4 edges in flight via 2 accumulators. FINAL adds reassociated epilogue.
template <bool FINAL>
__global__ __launch_bounds__(256) void gather_kernel(
    const int* __restrict__ rowptr, const int2* __restrict__ meta,
    const float* __restrict__ gsrc, const float* __restrict__ zorig,
    const float* __restrict__ c, const float* __restrict__ cc,
    float* __restrict__ outp) {
  int t = (int)threadIdx.x, lane = t & 63;
  int wid = (int)((blockIdx.x * blockDim.x + t) >> 6);
  int nw = (int)((gridDim.x * blockDim.x) >> 6);
  float cl = FINAL ? c[lane] : 0.f;
  float ccl = FINAL ? cc[lane] : 0.f;

  for (int n = wid; n < N_NODES; n += nw) {
    int lo = rowptr[n], hi = rowptr[n + 1];
    float acc0 = 0.f, acc1 = 0.f, wsum = 0.f;
    for (int j0 = lo; j0 < hi; j0 += 64) {
      int j = j0 + lane;
      int2 m = (j < hi) ? meta[j] : make_int2(0, 0);
      int cnt = min(hi - j0, 64);
      int k = 0;
      for (; k + 4 <= cnt; k += 4) {
        int s0 = __shfl(m.x, k), s1 = __shfl(m.x, k + 1);
        int s2 = __shfl(m.x, k + 2), s3 = __shfl(m.x, k + 3);
        float w0 = __int_as_float(__shfl(m.y, k));
        float w1 = __int_as_float(__shfl(m.y, k + 1));
        float w2 = __int_as_float(__shfl(m.y, k + 2));
        float w3 = __int_as_float(__shfl(m.y, k + 3));
        float v0 = gsrc[(size_t)s0 * D + lane];
        float v1 = gsrc[(size_t)s1 * D + lane];
        float v2 = gsrc[(size_t)s2 * D + lane];
        float v3 = gsrc[(size_t)s3 * D + lane];
        acc0 = fmaf(v0, w0, acc0);
        acc1 = fmaf(v1, w1, acc1);
        acc0 = fmaf(v2, w2, acc0);
        acc1 = fmaf(v3, w3, acc1);
        if (FINAL) wsum += (w0 + w1) + (w2 + w3);
      }
      for (; k < cnt; ++k) {
        int sk = __shfl(m.x, k);
        float wk = __int_as_float(__shfl(m.y, k));
        acc0 = fmaf(gsrc[(size_t)sk * D + lane], wk, acc0);
        if (FINAL) wsum += wk;
      }
    }
    float acc = acc0 + acc1;
    if (FINAL) {
      float t1n = gsrc[(size_t)n * D + lane];  // gsrc == t1 here
      float zn = zorig[(size_t)n * D + lane];
      outp[(size_t)n * D + lane] =
          0.25f * acc + 0.5f * t1n + 0.25f * zn + 0.5f * wsum * cl + ccl;
    } else {
      outp[(size_t)n * D + lane] = acc;
    }
  }
}

extern "C" void kernel_launch(void* const* d_in, const int* in_sizes, int n_in,
                              void* d_out, int out_size, void* d_ws, size_t ws_size,
                              hipStream_t stream) {
  const int* edge_index = (const int*)d_in[0];
  const int* src = edge_index;          // row 0
  const int* dst = edge_index + NUM_E;  // row 1
  const float* w = (const float*)d_in[1];
  const float* user_emb = (const float*)d_in[2];
  const float* item_emb = (const float*)d_in[3];
  const float* W1 = (const float*)d_in[4];
  const float* b1 = (const float*)d_in[5];
  const float* W2 = (const float*)d_in[6];
  const float* b2 = (const float*)d_in[7];
  float* out = (float*)d_out;

  // workspace layout (~78.1 MB, within the proven footprint)
  float* z = (float*)d_ws;                           // N*D floats (25.6 MB)
  float* t1 = z + (size_t)N_NODES * D;               // N*D floats (25.6 MB)
  int2* meta = (int2*)(t1 + (size_t)N_NODES * D);    // E int2 (25.6 MB)
  int* rowptr = (int*)(meta + NUM_E);                // N+1 (pad 100352)
  int* gcnt = rowptr + 100352;                       // NB*PBLK
  int* off = gcnt + NB * PBLK;                       // NB*PBLK
  int* tot = off + NB * PBLK;                        // NB (pad 392)
  int* bbase = tot + 392;                            // NB+1 (pad 392)
  float* Mbuf = (float*)(bbase + 392);               // 4096
  float* cbuf = Mbuf + 4096;                         // 64
  float* ccbuf = cbuf + 64;                          // 64
  // staging aliases t1: consumed by csr_finalize before gather<false> writes t1
  int2* staging = (int2*)t1;

  hipMemsetAsync(tot, 0, NB * sizeof(int), stream);

  micro_kernel<<<1, 256, 0, stream>>>(W1, W2, b1, b2, Mbuf, cbuf, ccbuf);
  zmm_kernel<<<(N_NODES + 63) / 64, 256, 0, stream>>>(user_emb, item_emb, Mbuf, z);

  p1_hist<<<PBLK, 256, 0, stream>>>((const int4*)dst, gcnt, tot);
  p2_scan<<<1, 512, 0, stream>>>(tot, bbase, rowptr);
  p2_off<<<NB, 256, 0, stream>>>(gcnt, bbase, off);
  p3_part<<<PBLK, 256, 0, stream>>>((const int4*)src, (const int4*)dst,
                                    (const float4*)w, off, staging);
  csr_finalize<<<NB, 256, 0, stream>>>(bbase, staging, meta, rowptr);

  // t1 = S @ z   (overwrites staging -- already consumed)
  gather_kernel<false><<<2048, 256, 0, stream>>>(rowptr, meta, z, z, cbuf, ccbuf, t1);
  // out = 0.25*S@t1 + 0.5*t1 + 0.25*z + 0.5*dw*c + cc
  gather_kernel<true><<<2048, 256, 0, stream>>>(rowptr, meta, t1, z, cbuf, ccbuf, out);
}

// Round 10
// 415.023 us; speedup vs baseline: 7.2878x; 1.2008x over previous
//
#include <hip/hip_runtime.h>

#define N_NODES 100000
#define NUM_U 50000
#define D 64
#define NUM_E 3200000
#define NB 391                 // ceil(100000/256) buckets of 256 dst nodes
#define PBLK 256               // partition blocks
#define CHUNK (NUM_E / PBLK)   // 12500 edges per partition block

__device__ __forceinline__ float bf2f(unsigned short u) {
  return __uint_as_float((unsigned)u << 16);
}
__device__ __forceinline__ unsigned short f2bf(float f) {
  unsigned u = __float_as_uint(f);
  u += 0x7FFF + ((u >> 16) & 1);  // RNE
  return (unsigned short)(u >> 16);
}

// ---- micro: M = (W2@W1)^T (row k, col j), c = b1@W2^T, cc = 0.5c+b2 ----
__global__ __launch_bounds__(256) void micro_kernel(
    const float* __restrict__ W1, const float* __restrict__ W2,
    const float* __restrict__ b1, const float* __restrict__ b2,
    float* __restrict__ M, float* __restrict__ c, float* __restrict__ cc) {
  __shared__ float w1[64][65], w2[64][65];
  int t = (int)threadIdx.x;
  for (int i = t; i < 4096; i += 256) { w1[i >> 6][i & 63] = W1[i]; w2[i >> 6][i & 63] = W2[i]; }
  __syncthreads();
  for (int i = t; i < 4096; i += 256) {
    int k = i >> 6, j = i & 63;
    float s = 0.f;
#pragma unroll
    for (int tt = 0; tt < 64; ++tt) s = fmaf(w2[j][tt], w1[tt][k], s);
    M[i] = s;  // M[k][j]
  }
  if (t < 64) {
    float s = 0.f;
#pragma unroll
    for (int tt = 0; tt < 64; ++tt) s = fmaf(b1[tt], w2[t][tt], s);
    c[t] = s;
    cc[t] = 0.5f * s + b2[t];
  }
}

// ---- z = x @ M, stored bf16 (x = concat(user,item) via pointer select) ----
__global__ __launch_bounds__(256) void zmm_kernel(
    const float* __restrict__ xu, const float* __restrict__ xi,
    const float* __restrict__ M, unsigned short* __restrict__ z16) {
  __shared__ float Mt[64][65];  // Mt[j][k] = M[k][j]
  __shared__ float U[64][65];
  int t = (int)threadIdx.x;
  for (int i = t; i < 4096; i += 256) Mt[i & 63][i >> 6] = M[i];
  int lane = t & 63, row = t >> 6;
  int n0 = (int)blockIdx.x * 64;
#pragma unroll
  for (int i = 0; i < 16; ++i) {
    int nl = row + 4 * i, n = n0 + nl;
    if (n < N_NODES) {
      const float* xr = (n < NUM_U) ? (xu + (size_t)n * D) : (xi + (size_t)(n - NUM_U) * D);
      U[nl][lane] = xr[lane];
    }
  }
  __syncthreads();
#pragma unroll
  for (int i = 0; i < 16; ++i) {
    int nl = row + 4 * i, n = n0 + nl;
    if (n >= N_NODES) continue;
    float s = 0.f;
#pragma unroll
    for (int k = 0; k < 64; ++k) s = fmaf(U[nl][k], Mt[lane][k], s);
    z16[(size_t)n * D + lane] = f2bf(s);
  }
}

// ---- P1: per-block bucket histogram (LDS) + global totals ----
__global__ __launch_bounds__(256) void p1_hist(const int4* __restrict__ dst4,
                                               int* __restrict__ gcnt,
                                               int* __restrict__ tot) {
  __shared__ int h[NB];
  int t = (int)threadIdx.x, blk = (int)blockIdx.x;
  for (int i = t; i < NB; i += 256) h[i] = 0;
  __syncthreads();
  int base4 = blk * (CHUNK / 4);
  for (int i = t; i < CHUNK / 4; i += 256) {
    int4 d = dst4[base4 + i];
    atomicAdd(&h[d.x >> 8], 1); atomicAdd(&h[d.y >> 8], 1);
    atomicAdd(&h[d.z >> 8], 1); atomicAdd(&h[d.w >> 8], 1);
  }
  __syncthreads();
  for (int i = t; i < NB; i += 256) {
    gcnt[i * PBLK + blk] = h[i];
    atomicAdd(&tot[i], h[i]);
  }
}

// ---- P2a: exclusive scan of bucket totals -> bbase; also rowptr[N]=E ----
__global__ __launch_bounds__(512) void p2_scan(const int* __restrict__ tot,
                                               int* __restrict__ bbase,
                                               int* __restrict__ rowptr) {
  __shared__ int ps[512];
  int t = (int)threadIdx.x;
  int v = (t < NB) ? tot[t] : 0;
  ps[t] = v;
  __syncthreads();
  for (int off = 1; off < 512; off <<= 1) {
    int a = (t >= off) ? ps[t - off] : 0;
    __syncthreads();
    ps[t] += a;
    __syncthreads();
  }
  if (t < NB) bbase[t] = ps[t] - v;
  if (t == 0) { bbase[NB] = NUM_E; rowptr[N_NODES] = NUM_E; }
}

// ---- P2b: per-(bucket,block) write offsets ----
__global__ __launch_bounds__(256) void p2_off(const int* __restrict__ gcnt,
                                              const int* __restrict__ bbase,
                                              int* __restrict__ off) {
  __shared__ int ps[256];
  int t = (int)threadIdx.x, b = (int)blockIdx.x;
  int v = gcnt[b * PBLK + t];
  ps[t] = v;
  __syncthreads();
  for (int o = 1; o < 256; o <<= 1) {
    int a = (t >= o) ? ps[t - o] : 0;
    __syncthreads();
    ps[t] += a;
    __syncthreads();
  }
  off[b * PBLK + t] = bbase[b] + ps[t] - v;
}

// ---- P3: partition edges into dense bucket-major staging ----
__global__ __launch_bounds__(256) void p3_part(const int4* __restrict__ src4,
                                               const int4* __restrict__ dst4,
                                               const float4* __restrict__ w4,
                                               const int* __restrict__ off,
                                               int2* __restrict__ staging) {
  __shared__ int cur[NB];
  int t = (int)threadIdx.x, blk = (int)blockIdx.x;
  for (int i = t; i < NB; i += 256) cur[i] = off[i * PBLK + blk];
  __syncthreads();
  int base4 = blk * (CHUNK / 4);
  for (int i = t; i < CHUNK / 4; i += 256) {
    int4 s = src4[base4 + i];
    int4 d = dst4[base4 + i];
    float4 w = w4[base4 + i];
    int p;
    p = atomicAdd(&cur[d.x >> 8], 1);
    staging[p] = make_int2(s.x | ((d.x & 255) << 17), __float_as_int(w.x));
    p = atomicAdd(&cur[d.y >> 8], 1);
    staging[p] = make_int2(s.y | ((d.y & 255) << 17), __float_as_int(w.y));
    p = atomicAdd(&cur[d.z >> 8], 1);
    staging[p] = make_int2(s.z | ((d.z & 255) << 17), __float_as_int(w.z));
    p = atomicAdd(&cur[d.w >> 8], 1);
    staging[p] = make_int2(s.w | ((d.w & 255) << 17), __float_as_int(w.w));
  }
}

// ---- F: per-bucket CSR finalize (writes stay in bucket's 64KB range) ----
__global__ __launch_bounds__(256) void csr_finalize(
    const int* __restrict__ bbase, const int2* __restrict__ staging,
    int2* __restrict__ meta, int* __restrict__ rowptr) {
  __shared__ int hist[256];
  __shared__ int ps[256];
  __shared__ int cur[256];
  int t = (int)threadIdx.x, b = (int)blockIdx.x;
  int bs = bbase[b], be = bbase[b + 1];
  hist[t] = 0;
  __syncthreads();
  for (int i = bs + t; i < be; i += 256) atomicAdd(&hist[staging[i].x >> 17], 1);
  __syncthreads();
  int v = hist[t];
  ps[t] = v;
  __syncthreads();
  for (int o = 1; o < 256; o <<= 1) {
    int a = (t >= o) ? ps[t - o] : 0;
    __syncthreads();
    ps[t] += a;
    __syncthreads();
  }
  int base = bs + ps[t] - v;  // exclusive
  cur[t] = base;
  int n = b * 256 + t;
  if (n < N_NODES) rowptr[n] = base;
  __syncthreads();
  for (int i = bs + t; i < be; i += 256) {
    int2 m = staging[i];
    int dl = m.x >> 17;
    int p = atomicAdd(&cur[dl], 1);
    meta[p] = make_int2(m.x & 0x1FFFF, m.y);
  }
}

// ---- G: gather, bf16 operand, scalar (wave-uniform) metadata, 8-deep unroll.
// FINAL adds the reassociated epilogue (f32 output).
template <bool FINAL>
__global__ __launch_bounds__(256) void gather_kernel(
    const int* __restrict__ rowptr, const int2* __restrict__ meta,
    const unsigned short* __restrict__ gsrc, const unsigned short* __restrict__ z16,
    const float* __restrict__ c, const float* __restrict__ cc,
    float* __restrict__ outf, unsigned short* __restrict__ out16) {
  int t = (int)threadIdx.x, lane = t & 63;
  int wid = (int)((blockIdx.x * blockDim.x + t) >> 6);
  int nw = (int)((gridDim.x * blockDim.x) >> 6);
  float cl = FINAL ? c[lane] : 0.f;
  float ccl = FINAL ? cc[lane] : 0.f;

  for (int n = wid; n < N_NODES; n += nw) {
    int lo = __builtin_amdgcn_readfirstlane(rowptr[n]);
    int hi = __builtin_amdgcn_readfirstlane(rowptr[n + 1]);
    float acc0 = 0.f, acc1 = 0.f, wsum = 0.f;
    int j = lo;
    for (; j + 8 <= hi; j += 8) {
      int2 m0 = meta[j + 0], m1 = meta[j + 1], m2 = meta[j + 2], m3 = meta[j + 3];
      int2 m4 = meta[j + 4], m5 = meta[j + 5], m6 = meta[j + 6], m7 = meta[j + 7];
      float v0 = bf2f(gsrc[((size_t)m0.x << 6) + lane]);
      float v1 = bf2f(gsrc[((size_t)m1.x << 6) + lane]);
      float v2 = bf2f(gsrc[((size_t)m2.x << 6) + lane]);
      float v3 = bf2f(gsrc[((size_t)m3.x << 6) + lane]);
      float v4 = bf2f(gsrc[((size_t)m4.x << 6) + lane]);
      float v5 = bf2f(gsrc[((size_t)m5.x << 6) + lane]);
      float v6 = bf2f(gsrc[((size_t)m6.x << 6) + lane]);
      float v7 = bf2f(gsrc[((size_t)m7.x << 6) + lane]);
      acc0 = fmaf(v0, __int_as_float(m0.y), acc0);
      acc1 = fmaf(v1, __int_as_float(m1.y), acc1);
      acc0 = fmaf(v2, __int_as_float(m2.y), acc0);
      acc1 = fmaf(v3, __int_as_float(m3.y), acc1);
      acc0 = fmaf(v4, __int_as_float(m4.y), acc0);
      acc1 = fmaf(v5, __int_as_float(m5.y), acc1);
      acc0 = fmaf(v6, __int_as_float(m6.y), acc0);
      acc1 = fmaf(v7, __int_as_float(m7.y), acc1);
      if (FINAL) {
        float wa = (__int_as_float(m0.y) + __int_as_float(m1.y)) +
                   (__int_as_float(m2.y) + __int_as_float(m3.y));
        float wb = (__int_as_float(m4.y) + __int_as_float(m5.y)) +
                   (__int_as_float(m6.y) + __int_as_float(m7.y));
        wsum += wa + wb;
      }
    }
    for (; j < hi; ++j) {
      int2 m = meta[j];
      acc0 = fmaf(bf2f(gsrc[((size_t)m.x << 6) + lane]), __int_as_float(m.y), acc0);
      if (FINAL) wsum += __int_as_float(m.y);
    }
    float acc = acc0 + acc1;
    size_t o = ((size_t)n << 6) + lane;
    if (FINAL) {
      float t1n = bf2f(gsrc[o]);  // gsrc == t1 here
      float zn = bf2f(z16[o]);
      outf[o] = 0.25f * acc + 0.5f * t1n + 0.25f * zn + 0.5f * wsum * cl + ccl;
    } else {
      out16[o] = f2bf(acc);
    }
  }
}

extern "C" void kernel_launch(void* const* d_in, const int* in_sizes, int n_in,
                              void* d_out, int out_size, void* d_ws, size_t ws_size,
                              hipStream_t stream) {
  const int* edge_index = (const int*)d_in[0];
  const int* src = edge_index;          // row 0
  const int* dst = edge_index + NUM_E;  // row 1
  const float* w = (const float*)d_in[1];
  const float* user_emb = (const float*)d_in[2];
  const float* item_emb = (const float*)d_in[3];
  const float* W1 = (const float*)d_in[4];
  const float* b1 = (const float*)d_in[5];
  const float* W2 = (const float*)d_in[6];
  const float* b2 = (const float*)d_in[7];
  float* out = (float*)d_out;

  // workspace layout (~65.5 MB)
  unsigned short* z16 = (unsigned short*)d_ws;          // N*D bf16 (12.8 MB)
  int2* staging = (int2*)(z16 + (size_t)N_NODES * D);   // E int2 (25.6 MB)
  unsigned short* t1_16 = (unsigned short*)staging;     // alias: staging dead after finalize
  int2* meta = staging + NUM_E;                         // E int2 (25.6 MB)
  int* rowptr = (int*)(meta + NUM_E);                   // N+1 (pad 100352)
  int* gcnt = rowptr + 100352;                          // NB*PBLK
  int* off = gcnt + NB * PBLK;                          // NB*PBLK
  int* tot = off + NB * PBLK;                           // NB (pad 392)
  int* bbase = tot + 392;                               // NB+1 (pad 392)
  float* Mbuf = (float*)(bbase + 392);                  // 4096
  float* cbuf = Mbuf + 4096;                            // 64
  float* ccbuf = cbuf + 64;                             // 64

  hipMemsetAsync(tot, 0, NB * sizeof(int), stream);

  micro_kernel<<<1, 256, 0, stream>>>(W1, W2, b1, b2, Mbuf, cbuf, ccbuf);
  zmm_kernel<<<(N_NODES + 63) / 64, 256, 0, stream>>>(user_emb, item_emb, Mbuf, z16);

  p1_hist<<<PBLK, 256, 0, stream>>>((const int4*)dst, gcnt, tot);
  p2_scan<<<1, 512, 0, stream>>>(tot, bbase, rowptr);
  p2_off<<<NB, 256, 0, stream>>>(gcnt, bbase, off);
  p3_part<<<PBLK, 256, 0, stream>>>((const int4*)src, (const int4*)dst,
                                    (const float4*)w, off, staging);
  csr_finalize<<<NB, 256, 0, stream>>>(bbase, staging, meta, rowptr);

  // t1 = S @ z   (bf16 store; overwrites dead staging region)
  gather_kernel<false><<<2048, 256, 0, stream>>>(rowptr, meta, z16, z16, cbuf,
                                                 ccbuf, nullptr, t1_16);
  // out = 0.25*S@t1 + 0.5*t1 + 0.25*z + 0.5*dw*c + cc  (f32 output)
  gather_kernel<true><<<2048, 256, 0, stream>>>(rowptr, meta, t1_16, z16, cbuf,
                                                ccbuf, out, nullptr);
}

// Round 11
// 413.707 us; speedup vs baseline: 7.3110x; 1.0032x over previous
//
#include <hip/hip_runtime.h>

#define N_NODES 100000
#define NUM_U 50000
#define D 64
#define NUM_E 3200000
#define NB 391                 // ceil(100000/256) buckets of 256 dst nodes
#define PBLK 500               // partition blocks
#define CHUNK (NUM_E / PBLK)   // 6400 edges per partition block
#define CHUNK4 (CHUNK / 4)     // 1600
#define FCAP 8928              // finalize LDS capacity (mean 8192 + 8 sigma)

__device__ __forceinline__ float bf2f(unsigned short u) {
  return __uint_as_float((unsigned)u << 16);
}
__device__ __forceinline__ unsigned short f2bf(float f) {
  unsigned u = __float_as_uint(f);
  u += 0x7FFF + ((u >> 16) & 1);  // RNE
  return (unsigned short)(u >> 16);
}

// ---- micro: M = (W2@W1)^T (row k, col j), c = b1@W2^T, cc = 0.5c+b2 ----
__global__ __launch_bounds__(256) void micro_kernel(
    const float* __restrict__ W1, const float* __restrict__ W2,
    const float* __restrict__ b1, const float* __restrict__ b2,
    float* __restrict__ M, float* __restrict__ c, float* __restrict__ cc) {
  __shared__ float w1[64][65], w2[64][65];
  int t = (int)threadIdx.x;
  for (int i = t; i < 4096; i += 256) { w1[i >> 6][i & 63] = W1[i]; w2[i >> 6][i & 63] = W2[i]; }
  __syncthreads();
  for (int i = t; i < 4096; i += 256) {
    int k = i >> 6, j = i & 63;
    float s = 0.f;
#pragma unroll
    for (int tt = 0; tt < 64; ++tt) s = fmaf(w2[j][tt], w1[tt][k], s);
    M[i] = s;  // M[k][j]
  }
  if (t < 64) {
    float s = 0.f;
#pragma unroll
    for (int tt = 0; tt < 64; ++tt) s = fmaf(b1[tt], w2[t][tt], s);
    c[t] = s;
    cc[t] = 0.5f * s + b2[t];
  }
}

// ---- z = x @ M, stored bf16 ----
__global__ __launch_bounds__(256) void zmm_kernel(
    const float* __restrict__ xu, const float* __restrict__ xi,
    const float* __restrict__ M, unsigned short* __restrict__ z16) {
  __shared__ float Mt[64][65];
  __shared__ float U[64][65];
  int t = (int)threadIdx.x;
  for (int i = t; i < 4096; i += 256) Mt[i & 63][i >> 6] = M[i];
  int lane = t & 63, row = t >> 6;
  int n0 = (int)blockIdx.x * 64;
#pragma unroll
  for (int i = 0; i < 16; ++i) {
    int nl = row + 4 * i, n = n0 + nl;
    if (n < N_NODES) {
      const float* xr = (n < NUM_U) ? (xu + (size_t)n * D) : (xi + (size_t)(n - NUM_U) * D);
      U[nl][lane] = xr[lane];
    }
  }
  __syncthreads();
#pragma unroll
  for (int i = 0; i < 16; ++i) {
    int nl = row + 4 * i, n = n0 + nl;
    if (n >= N_NODES) continue;
    float s = 0.f;
#pragma unroll
    for (int k = 0; k < 64; ++k) s = fmaf(U[nl][k], Mt[lane][k], s);
    z16[(size_t)n * D + lane] = f2bf(s);
  }
}

// ---- P1: bucket totals only ----
__global__ __launch_bounds__(256) void p1_hist(const int4* __restrict__ dst4,
                                               int* __restrict__ tot) {
  __shared__ int h[NB];
  int t = (int)threadIdx.x, blk = (int)blockIdx.x;
  for (int i = t; i < NB; i += 256) h[i] = 0;
  __syncthreads();
  int base4 = blk * CHUNK4;
  for (int i = t; i < CHUNK4; i += 256) {
    int4 d = dst4[base4 + i];
    atomicAdd(&h[d.x >> 8], 1); atomicAdd(&h[d.y >> 8], 1);
    atomicAdd(&h[d.z >> 8], 1); atomicAdd(&h[d.w >> 8], 1);
  }
  __syncthreads();
  for (int i = t; i < NB; i += 256)
    if (h[i]) atomicAdd(&tot[i], h[i]);
}

// ---- P2: scan bucket totals -> bbase (pristine) + gcursor (bump-allocated) ----
__global__ __launch_bounds__(512) void p2_scan(const int* __restrict__ tot,
                                               int* __restrict__ bbase,
                                               int* __restrict__ gcursor,
                                               int* __restrict__ rowptr) {
  __shared__ int ps[512];
  int t = (int)threadIdx.x;
  int v = (t < NB) ? tot[t] : 0;
  ps[t] = v;
  __syncthreads();
  for (int o = 1; o < 512; o <<= 1) {
    int a = (t >= o) ? ps[t - o] : 0;
    __syncthreads();
    ps[t] += a;
    __syncthreads();
  }
  if (t < NB) { int e = ps[t] - v; bbase[t] = e; gcursor[t] = e; }
  if (t == 0) { bbase[NB] = NUM_E; rowptr[N_NODES] = NUM_E; }
}

// ---- P3: LDS radix-partition per chunk; coalesced run writes; atomic bump
// run allocation on gcursor (within-bucket block order nondeterministic ->
// only fp-sum reorder downstream, same tolerance as before).
__global__ __launch_bounds__(512) void p3_part(const int4* __restrict__ src4,
                                               const int4* __restrict__ dst4,
                                               const float4* __restrict__ w4,
                                               int* __restrict__ gcursor,
                                               int2* __restrict__ staging) {
  __shared__ int2 ent[CHUNK];   // 51.2 KB
  __shared__ int h[NB];         // hist -> cursor
  __shared__ int lst[NB + 1];   // local run starts
  __shared__ int og[NB];        // global run bases
  __shared__ int ps[512];
  int t = (int)threadIdx.x, blk = (int)blockIdx.x;
  for (int i = t; i < NB; i += 512) h[i] = 0;
  __syncthreads();
  int base4 = blk * CHUNK4;
  for (int i = t; i < CHUNK4; i += 512) {
    int4 d = dst4[base4 + i];
    atomicAdd(&h[d.x >> 8], 1); atomicAdd(&h[d.y >> 8], 1);
    atomicAdd(&h[d.z >> 8], 1); atomicAdd(&h[d.w >> 8], 1);
  }
  __syncthreads();
  int v = (t < NB) ? h[t] : 0;
  ps[t] = v;
  __syncthreads();
  for (int o = 1; o < 512; o <<= 1) {
    int a = (t >= o) ? ps[t - o] : 0;
    __syncthreads();
    ps[t] += a;
    __syncthreads();
  }
  if (t < NB) {
    lst[t] = ps[t] - v;
    og[t] = v ? atomicAdd(&gcursor[t], v) : 0;
  }
  if (t == 0) lst[NB] = CHUNK;
  __syncthreads();
  if (t < NB) h[t] = lst[t];  // reuse as cursor
  __syncthreads();
  for (int i = t; i < CHUNK4; i += 512) {
    int4 s = src4[base4 + i];
    int4 d = dst4[base4 + i];
    float4 w = w4[base4 + i];
    int p;
    p = atomicAdd(&h[d.x >> 8], 1);
    ent[p] = make_int2(s.x | ((d.x & 255) << 17), __float_as_int(w.x));
    p = atomicAdd(&h[d.y >> 8], 1);
    ent[p] = make_int2(s.y | ((d.y & 255) << 17), __float_as_int(w.y));
    p = atomicAdd(&h[d.z >> 8], 1);
    ent[p] = make_int2(s.z | ((d.z & 255) << 17), __float_as_int(w.z));
    p = atomicAdd(&h[d.w >> 8], 1);
    ent[p] = make_int2(s.w | ((d.w & 255) << 17), __float_as_int(w.w));
  }
  __syncthreads();
  // coalesced output: consecutive i within a run -> consecutive global addrs
  for (int i = t; i < CHUNK; i += 512) {
    int lo = 0, hi = NB;  // largest b with lst[b] <= i
    while (hi - lo > 1) { int mid = (lo + hi) >> 1; if (lst[mid] <= i) lo = mid; else hi = mid; }
    staging[og[lo] + (i - lst[lo])] = ent[i];
  }
}

// ---- F: per-bucket CSR finalize, LDS sort + coalesced meta write ----
__global__ __launch_bounds__(256) void csr_finalize(
    const int* __restrict__ bbase, const int2* __restrict__ staging,
    int2* __restrict__ meta, int* __restrict__ rowptr) {
  __shared__ int2 ent[FCAP];  // 71.4 KB
  __shared__ int hist[256], ps[256], cur[256];
  int t = (int)threadIdx.x, b = (int)blockIdx.x;
  int bs = bbase[b], be = bbase[b + 1];
  int cnt = be - bs;
  hist[t] = 0;
  __syncthreads();
  for (int i = bs + t; i < be; i += 256) atomicAdd(&hist[staging[i].x >> 17], 1);
  __syncthreads();
  int v = hist[t];
  ps[t] = v;
  __syncthreads();
  for (int o = 1; o < 256; o <<= 1) {
    int a = (t >= o) ? ps[t - o] : 0;
    __syncthreads();
    ps[t] += a;
    __syncthreads();
  }
  int lexcl = ps[t] - v;
  int n = b * 256 + t;
  if (n < N_NODES) rowptr[n] = bs + lexcl;
  if (cnt <= FCAP) {
    cur[t] = lexcl;
    __syncthreads();
    for (int i = bs + t; i < be; i += 256) {
      int2 m = staging[i];
      int p = atomicAdd(&cur[m.x >> 17], 1);
      ent[p] = make_int2(m.x & 0x1FFFF, m.y);
    }
    __syncthreads();
    for (int i = t; i < cnt; i += 256) meta[bs + i] = ent[i];
  } else {  // fallback: scattered global writes (correctness guard)
    cur[t] = bs + lexcl;
    __syncthreads();
    for (int i = bs + t; i < be; i += 256) {
      int2 m = staging[i];
      int p = atomicAdd(&cur[m.x >> 17], 1);
      meta[p] = make_int2(m.x & 0x1FFFF, m.y);
    }
  }
}

// ---- G: gather, bf16 operand, scalar metadata, 16/4/1 unroll tiers ----
template <bool FINAL>
__global__ __launch_bounds__(256) void gather_kernel(
    const int* __restrict__ rowptr, const int2* __restrict__ meta,
    const unsigned short* __restrict__ gsrc, const unsigned short* __restrict__ z16,
    const float* __restrict__ c, const float* __restrict__ cc,
    float* __restrict__ outf, unsigned short* __restrict__ out16) {
  int t = (int)threadIdx.x, lane = t & 63;
  int wid = (int)((blockIdx.x * blockDim.x + t) >> 6);
  int nw = (int)((gridDim.x * blockDim.x) >> 6);
  float cl = FINAL ? c[lane] : 0.f;
  float ccl = FINAL ? cc[lane] : 0.f;

  for (int n = wid; n < N_NODES; n += nw) {
    int lo = __builtin_amdgcn_readfirstlane(rowptr[n]);
    int hi = __builtin_amdgcn_readfirstlane(rowptr[n + 1]);
    float acc0 = 0.f, acc1 = 0.f, wsum = 0.f;
    int j = lo;
    for (; j + 16 <= hi; j += 16) {
      int2 mm[16];
      float vv[16];
#pragma unroll
      for (int q = 0; q < 16; ++q) mm[q] = meta[j + q];
#pragma unroll
      for (int q = 0; q < 16; ++q) vv[q] = bf2f(gsrc[((size_t)mm[q].x << 6) + lane]);
#pragma unroll
      for (int q = 0; q < 16; ++q) {
        if (q & 1) acc1 = fmaf(vv[q], __int_as_float(mm[q].y), acc1);
        else       acc0 = fmaf(vv[q], __int_as_float(mm[q].y), acc0);
      }
      if (FINAL) {
        float s0 = 0.f, s1 = 0.f;
#pragma unroll
        for (int q = 0; q < 16; q += 2) {
          s0 += __int_as_float(mm[q].y);
          s1 += __int_as_float(mm[q + 1].y);
        }
        wsum += s0 + s1;
      }
    }
    for (; j + 4 <= hi; j += 4) {
      int2 m0 = meta[j + 0], m1 = meta[j + 1], m2 = meta[j + 2], m3 = meta[j + 3];
      float v0 = bf2f(gsrc[((size_t)m0.x << 6) + lane]);
      float v1 = bf2f(gsrc[((size_t)m1.x << 6) + lane]);
      float v2 = bf2f(gsrc[((size_t)m2.x << 6) + lane]);
      float v3 = bf2f(gsrc[((size_t)m3.x << 6) + lane]);
      acc0 = fmaf(v0, __int_as_float(m0.y), acc0);
      acc1 = fmaf(v1, __int_as_float(m1.y), acc1);
      acc0 = fmaf(v2, __int_as_float(m2.y), acc0);
      acc1 = fmaf(v3, __int_as_float(m3.y), acc1);
      if (FINAL)
        wsum += (__int_as_float(m0.y) + __int_as_float(m1.y)) +
                (__int_as_float(m2.y) + __int_as_float(m3.y));
    }
    for (; j < hi; ++j) {
      int2 m = meta[j];
      acc0 = fmaf(bf2f(gsrc[((size_t)m.x << 6) + lane]), __int_as_float(m.y), acc0);
      if (FINAL) wsum += __int_as_float(m.y);
    }
    float acc = acc0 + acc1;
    size_t o = ((size_t)n << 6) + lane;
    if (FINAL) {
      float t1n = bf2f(gsrc[o]);  // gsrc == t1 here
      float zn = bf2f(z16[o]);
      outf[o] = 0.25f * acc + 0.5f * t1n + 0.25f * zn + 0.5f * wsum * cl + ccl;
    } else {
      out16[o] = f2bf(acc);
    }
  }
}

extern "C" void kernel_launch(void* const* d_in, const int* in_sizes, int n_in,
                              void* d_out, int out_size, void* d_ws, size_t ws_size,
                              hipStream_t stream) {
  const int* edge_index = (const int*)d_in[0];
  const int* src = edge_index;          // row 0
  const int* dst = edge_index + NUM_E;  // row 1
  const float* w = (const float*)d_in[1];
  const float* user_emb = (const float*)d_in[2];
  const float* item_emb = (const float*)d_in[3];
  const float* W1 = (const float*)d_in[4];
  const float* b1 = (const float*)d_in[5];
  const float* W2 = (const float*)d_in[6];
  const float* b2 = (const float*)d_in[7];
  float* out = (float*)d_out;

  // workspace layout (~64.5 MB)
  unsigned short* z16 = (unsigned short*)d_ws;          // N*D bf16 (12.8 MB)
  int2* staging = (int2*)(z16 + (size_t)N_NODES * D);   // E int2 (25.6 MB)
  unsigned short* t1_16 = (unsigned short*)staging;     // alias: staging dead after finalize
  int2* meta = staging + NUM_E;                         // E int2 (25.6 MB)
  int* rowptr = (int*)(meta + NUM_E);                   // N+1 (pad 100352)
  int* tot = rowptr + 100352;                           // NB (pad 392)
  int* bbase = tot + 392;                               // NB+1 (pad 392)
  int* gcursor = bbase + 392;                           // NB (pad 392)
  float* Mbuf = (float*)(gcursor + 392);                // 4096
  float* cbuf = Mbuf + 4096;                            // 64
  float* ccbuf = cbuf + 64;                             // 64

  hipMemsetAsync(tot, 0, NB * sizeof(int), stream);

  micro_kernel<<<1, 256, 0, stream>>>(W1, W2, b1, b2, Mbuf, cbuf, ccbuf);
  zmm_kernel<<<(N_NODES + 63) / 64, 256, 0, stream>>>(user_emb, item_emb, Mbuf, z16);

  p1_hist<<<PBLK, 256, 0, stream>>>((const int4*)dst, tot);
  p2_scan<<<1, 512, 0, stream>>>(tot, bbase, gcursor, rowptr);
  p3_part<<<PBLK, 512, 0, stream>>>((const int4*)src, (const int4*)dst,
                                    (const float4*)w, gcursor, staging);
  csr_finalize<<<NB, 256, 0, stream>>>(bbase, staging, meta, rowptr);

  // t1 = S @ z   (bf16 store; overwrites dead staging region)
  gather_kernel<false><<<2048, 256, 0, stream>>>(rowptr, meta, z16, z16, cbuf,
                                                 ccbuf, nullptr, t1_16);
  // out = 0.25*S@t1 + 0.5*t1 + 0.25*z + 0.5*dw*c + cc  (f32 output)
  gather_kernel<true><<<2048, 256, 0, stream>>>(rowptr, meta, t1_16, z16, cbuf,
                                                ccbuf, out, nullptr);
}